// Round 7
// baseline (6298.508 us; speedup 1.0000x reference)
//
#include <hip/hip_runtime.h>
#include <stdint.h>

// Problem constants
#define BB   64
#define TT   512
#define HT   256
#define OO   128
#define GATES 1024   // 4*H

// ---------------------------------------------------------------------------
// R16 recurrence: R14 hybrid MFMA+fdot2, ALLOCATION-FIXED.
// R14 failed on a tiny in-loop scratch spill (WRITE +10MB -> 13000cy steps):
// the compiler left the 128-reg MFMA weight array in ARCH class.  R16 pins
// those frags to AGPR with asm("+a"), freeing arch for the fdot2 weights.
// R15 (4-CU split) showed cross-CU L3 sync costs ~2900cy/step -> sync-free
// 64-CU hybrid has the higher ceiling.
// Per-CU/step pipe budget: matrix 256KB=1242cy | LDS 98+38KB~1600cy |
// VALU fdot2 ~450cy | L1 stream 66KB~1030cy  -> step ~1800-2100cy.
// Layout per layer (32768 uint4):
//   A [0,16384):  MFMA frags ((w*32+rt*4+kt)*64+lane);
//                 row=128w+16rt+(lane&15), k=32kt+(lane>>4)*8
//   fdot2 (k[128,256), thread t: e=t>>7 k-slice, j=t&127 rows 8j..8j+7;
//   m-th uint4 at [16384 + m*512 + t], row offset r, u=k-subslice:
//     m 0..11  arch   rows 8j+0..2  (m=r*4+u)
//     m 12..23 LDS    rows 8j+3..5
//     m 24..31 stream rows 8j+6..7  (two 4-reg batches)

typedef _Float16 half_t;
typedef _Float16 half2_t __attribute__((ext_vector_type(2)));
typedef _Float16 f16x8  __attribute__((ext_vector_type(8)));
typedef float    f32x4  __attribute__((ext_vector_type(4)));

__device__ __forceinline__ half2_t h2_(unsigned int x) {
    return __builtin_bit_cast(half2_t, x);
}
// lgkm-only workgroup barrier: no vmcnt drain per step.
#define WG_BARRIER() do { __builtin_amdgcn_s_waitcnt(0xC07F); \
                          __builtin_amdgcn_s_barrier(); } while (0)

__device__ __forceinline__ float fast_sig(float x) {
    return __builtin_amdgcn_rcpf(1.0f + __expf(-x));
}
__device__ __forceinline__ float fast_tanh(float x) {
    float t = __expf(2.0f * x);
    return 1.0f - 2.0f * __builtin_amdgcn_rcpf(t + 1.0f);
}

// 8-element fp16 dot: acc += w . h  (w, h as uint4 of packed half2)
__device__ __forceinline__ float dot8(float acc, uint4 wv, uint4 h4) {
    acc = __builtin_amdgcn_fdot2(h2_(wv.x), h2_(h4.x), acc, false);
    acc = __builtin_amdgcn_fdot2(h2_(wv.y), h2_(h4.y), acc, false);
    acc = __builtin_amdgcn_fdot2(h2_(wv.z), h2_(h4.z), acc, false);
    acc = __builtin_amdgcn_fdot2(h2_(wv.w), h2_(h4.w), acc, false);
    return acc;
}

// ---------------------------------------------------------------------------
// Embedding gather + decoder_action output
__global__ __launch_bounds__(256) void embed_kernel(
    const int* __restrict__ actions, const float* __restrict__ emb_table,
    float* __restrict__ X, float* __restrict__ dact)
{
    int row = blockIdx.x;
    int t = row & (TT - 1);
    int id = (t == 0) ? 0 : actions[row - 1];
    X[(int64_t)row * HT + threadIdx.x] = emb_table[(int64_t)id * HT + threadIdx.x];
    if (threadIdx.x == 0) dact[row] = (float)actions[row];
}

// ---------------------------------------------------------------------------
// Repack Whh to the R16 layout (regions above).
__global__ __launch_bounds__(256) void repack_whh_mfma_kernel(
    const float* __restrict__ Whh, uint4* __restrict__ Wpkh)
{
    int idx = blockIdx.x * 256 + threadIdx.x;   // 0..65535
    int g = idx & 32767;
    int l = idx >> 15;
    int row, k;
    if (g < 16384) {                             // A: MFMA frags
        int lane = g & 63;
        int f = (g >> 6) & 31;                   // rt*4+kt
        int w = g >> 11;                         // 0..7
        int kt = f & 3, rt = f >> 2;
        row = 128 * w + 16 * rt + (lane & 15);
        k = 32 * kt + (lane >> 4) * 8;
    } else {                                     // fdot2 region
        int i = g - 16384;
        int t = i & 511;
        int m = i >> 9;                          // 0..31
        int e = t >> 7, j = t & 127;
        int r = m >> 2;                          // 0..7 (row offset)
        int u = m & 3;
        row = 8 * j + r;
        k = 128 + 32 * e + 8 * u;
    }
    const float* src = Whh + (int64_t)l * (GATES * HT) + (int64_t)row * HT + k;
    const float4 a = *(const float4*)(src);
    const float4 b = *(const float4*)(src + 4);
    half2_t p0 = {(half_t)a.x, (half_t)a.y};
    half2_t p1 = {(half_t)a.z, (half_t)a.w};
    half2_t p2 = {(half_t)b.x, (half_t)b.y};
    half2_t p3 = {(half_t)b.z, (half_t)b.w};
    uint4 o;
    o.x = __builtin_bit_cast(unsigned int, p0);
    o.y = __builtin_bit_cast(unsigned int, p1);
    o.z = __builtin_bit_cast(unsigned int, p2);
    o.w = __builtin_bit_cast(unsigned int, p3);
    Wpkh[idx] = o;
}

// ---------------------------------------------------------------------------
// MFMA fp16 GEMM: C = act( A @ op(B) + bias1 + bias2 ), fp32 in/out.
template<bool TRANS_B, int ACT>
__global__ __launch_bounds__(256) void mfma_gemm_kernel(
    const float* __restrict__ A, const float* __restrict__ Bm,
    float* __restrict__ C,
    int K, int lda, int ldb, int ldc,
    int64_t sA, int64_t sB, int64_t sC,
    const float* __restrict__ bias1, const float* __restrict__ bias2)
{
    constexpr int BM = 128, BN = 128, BK = 32;
    constexpr int LDT = BK + 8;                  // 40 halfs = 80 B row stride
    __shared__ __align__(16) half_t Asl[BM * LDT];   // 10 KB
    __shared__ __align__(16) half_t Bsl[BN * LDT];   // 10 KB

    const int tid  = threadIdx.x;
    const int wave = tid >> 6;
    const int lane = tid & 63;
    const int wm = (wave & 1) * 64;
    const int wn = (wave >> 1) * 64;
    const int m0 = blockIdx.y * BM;
    const int n0 = blockIdx.x * BN;
    A  += (int64_t)blockIdx.z * sA;
    Bm += (int64_t)blockIdx.z * sB;
    C  += (int64_t)blockIdx.z * sC;

    const int fm = lane & 15;
    const int qd = lane >> 4;

    f32x4 acc[4][4] = {};

    for (int k0 = 0; k0 < K; k0 += BK) {
        #pragma unroll
        for (int i = 0; i < 4; i++) {
            int idx = tid + i * 256;             // 0..1023
            int r  = idx >> 3;                   // 0..127
            int kq = idx & 7;                    // 0..7
            float4 v = *(const float4*)(A + (int64_t)(m0 + r) * lda + k0 + kq * 4);
            half_t* d = &Asl[r * LDT + kq * 4];
            d[0] = (half_t)v.x; d[1] = (half_t)v.y;
            d[2] = (half_t)v.z; d[3] = (half_t)v.w;
        }
        if (TRANS_B) {
            #pragma unroll
            for (int i = 0; i < 4; i++) {
                int idx = tid + i * 256;
                int r  = idx >> 3;
                int kq = idx & 7;
                float4 v = *(const float4*)(Bm + (int64_t)(n0 + r) * ldb + k0 + kq * 4);
                half_t* d = &Bsl[r * LDT + kq * 4];
                d[0] = (half_t)v.x; d[1] = (half_t)v.y;
                d[2] = (half_t)v.z; d[3] = (half_t)v.w;
            }
        } else {
            #pragma unroll
            for (int i = 0; i < 4; i++) {
                int idx = tid + i * 256;
                int kk = idx >> 5;               // 0..31
                int nq = idx & 31;               // 0..31 (x4 n)
                float4 v = *(const float4*)(Bm + (int64_t)(k0 + kk) * ldb + n0 + nq * 4);
                Bsl[(nq * 4 + 0) * LDT + kk] = (half_t)v.x;
                Bsl[(nq * 4 + 1) * LDT + kk] = (half_t)v.y;
                Bsl[(nq * 4 + 2) * LDT + kk] = (half_t)v.z;
                Bsl[(nq * 4 + 3) * LDT + kk] = (half_t)v.w;
            }
        }
        __syncthreads();

        f16x8 af[4], bf[4];
        #pragma unroll
        for (int t = 0; t < 4; t++)
            af[t] = *(const f16x8*)&Asl[(wm + t * 16 + fm) * LDT + qd * 8];
        #pragma unroll
        for (int t = 0; t < 4; t++)
            bf[t] = *(const f16x8*)&Bsl[(wn + t * 16 + fm) * LDT + qd * 8];
        #pragma unroll
        for (int mt = 0; mt < 4; mt++)
            #pragma unroll
            for (int nt = 0; nt < 4; nt++)
                acc[mt][nt] = __builtin_amdgcn_mfma_f32_16x16x32_f16(
                                  af[mt], bf[nt], acc[mt][nt], 0, 0, 0);
        __syncthreads();
    }

    #pragma unroll
    for (int nt = 0; nt < 4; nt++) {
        int n = n0 + wn + nt * 16 + fm;
        float bv = 0.0f;
        if (bias1) bv += bias1[n];
        if (bias2) bv += bias2[n];
        #pragma unroll
        for (int mt = 0; mt < 4; mt++) {
            #pragma unroll
            for (int r = 0; r < 4; r++) {
                int m = m0 + wm + mt * 16 + qd * 4 + r;
                float v = acc[mt][nt][r] + bv;
                if (ACT == 1) v = tanhf(v);
                C[(int64_t)m * ldc + n] = v;
            }
        }
    }
}

// ---------------------------------------------------------------------------
// Generic fp32 tiled GEMM (kept for attention + output chain precision).
template<bool TRANS_B, int ACT>
__global__ __launch_bounds__(256) void gemm128_kernel(
    const float* __restrict__ A, const float* __restrict__ Bm,
    float* __restrict__ C,
    int K, int lda, int ldb, int ldc,
    int64_t sA, int64_t sB, int64_t sC,
    const float* __restrict__ bias1, const float* __restrict__ bias2)
{
    constexpr int BM = 128, BN = 128, BK = 16;
    __shared__ __align__(16) float As[BK][BM + 4];
    __shared__ __align__(16) float Bs[BK][BN + 4];

    const int tid = threadIdx.x;
    const int m0 = blockIdx.y * BM;
    const int n0 = blockIdx.x * BN;
    A  += (int64_t)blockIdx.z * sA;
    Bm += (int64_t)blockIdx.z * sB;
    C  += (int64_t)blockIdx.z * sC;

    const int tm = tid & 15;
    const int tn = tid >> 4;

    float acc[8][8] = {};

    for (int k0 = 0; k0 < K; k0 += BK) {
        #pragma unroll
        for (int i = 0; i < 2; i++) {
            int idx = tid + i * 256;
            int ar = idx >> 2;
            int ak = (idx & 3) * 4;
            const float4 v = *(const float4*)(A + (int64_t)(m0 + ar) * lda + k0 + ak);
            As[ak + 0][ar] = v.x; As[ak + 1][ar] = v.y;
            As[ak + 2][ar] = v.z; As[ak + 3][ar] = v.w;
        }
        if (TRANS_B) {
            #pragma unroll
            for (int i = 0; i < 2; i++) {
                int idx = tid + i * 256;
                int br = idx >> 2;
                int bk = (idx & 3) * 4;
                const float4 v = *(const float4*)(Bm + (int64_t)(n0 + br) * ldb + k0 + bk);
                Bs[bk + 0][br] = v.x; Bs[bk + 1][br] = v.y;
                Bs[bk + 2][br] = v.z; Bs[bk + 3][br] = v.w;
            }
        } else {
            #pragma unroll
            for (int i = 0; i < 2; i++) {
                int idx = tid + i * 256;
                int bk = idx >> 5;
                int bn = (idx & 31) * 4;
                const float4 v = *(const float4*)(Bm + (int64_t)(k0 + bk) * ldb + n0 + bn);
                *(float4*)&Bs[bk][bn] = v;
            }
        }
        __syncthreads();

        #pragma unroll
        for (int k = 0; k < BK; k++) {
            float a[8], b[8];
            *(float4*)&a[0] = *(const float4*)&As[k][tm * 8];
            *(float4*)&a[4] = *(const float4*)&As[k][tm * 8 + 4];
            *(float4*)&b[0] = *(const float4*)&Bs[k][tn * 8];
            *(float4*)&b[4] = *(const float4*)&Bs[k][tn * 8 + 4];
            #pragma unroll
            for (int i = 0; i < 8; i++)
                #pragma unroll
                for (int j = 0; j < 8; j++)
                    acc[i][j] += a[i] * b[j];
        }
        __syncthreads();
    }

    float bv[8];
    #pragma unroll
    for (int j = 0; j < 8; j++) {
        int n = n0 + tn * 8 + j;
        float b = 0.0f;
        if (bias1) b += bias1[n];
        if (bias2) b += bias2[n];
        bv[j] = b;
    }
    #pragma unroll
    for (int i = 0; i < 8; i++) {
        int64_t m = m0 + tm * 8 + i;
        float o[8];
        #pragma unroll
        for (int j = 0; j < 8; j++) {
            float v = acc[i][j] + bv[j];
            if (ACT == 1) v = tanhf(v);
            o[j] = v;
        }
        *(float4*)(C + m * ldc + n0 + tn * 8)     = make_float4(o[0], o[1], o[2], o[3]);
        *(float4*)(C + m * ldc + n0 + tn * 8 + 4) = make_float4(o[4], o[5], o[6], o[7]);
    }
}

// ---------------------------------------------------------------------------
// LSTM recurrence (R16).  64 blocks x 512 threads, 1 block/CU, 2 waves/EU.
__global__ __launch_bounds__(512)
__attribute__((amdgpu_waves_per_eu(2, 2)))
void lstm_rec_kernel(
    const float* __restrict__ Ag,
    const uint4* __restrict__ Wpk,
    const float* __restrict__ h0l,
    const float* __restrict__ c0l,
    float* __restrict__ X, int ldx)
{
    const int b    = blockIdx.x;
    const int tid  = threadIdx.x;
    const int w    = tid >> 6;
    const int lane = tid & 63;
    const int quad = lane >> 4;
    const int e    = tid >> 7;       // fdot2 k-slice (0..3): k = 128+32e
    // rows 8j..8j+7 with j = tid & 127

    __shared__ __align__(16) uint4  wlds[12 * 512];    // 96 KB fdot2 LDS rows
    __shared__ __align__(16) float  gshF[4 * GATES];   // 16 KB fdot2 partials
    __shared__ __align__(16) float  gshM[GATES];       // 4 KB mfma partials
    __shared__ __align__(16) half_t hsh[HT];           // 512 B

    // A: MFMA frags -> PINNED to AGPR class (the R14 spill fix)
    f16x8 wm[32];
    #pragma unroll
    for (int f = 0; f < 32; f++)
        wm[f] = __builtin_bit_cast(f16x8, Wpk[(w * 32 + f) * 64 + lane]);
    #pragma unroll
    for (int f = 0; f < 32; f++)
        asm volatile("" : "+a"(wm[f]));
    // B: fdot2 arch rows 8j+0..2 (12 uint4 = 48 arch VGPR)
    const uint4* WsF = Wpk + 16384 + tid;
    uint4 wa[12];
    #pragma unroll
    for (int m = 0; m < 12; m++)
        wa[m] = WsF[m * 512];
    // C: fdot2 LDS rows 8j+3..5
    #pragma unroll
    for (int m = 0; m < 12; m++)
        wlds[m * 512 + tid] = WsF[(12 + m) * 512];

    if (tid < HT) hsh[tid] = (half_t)h0l[b * HT + tid];
    float c = (tid < HT) ? c0l[b * HT + tid] : 0.0f;
    __syncthreads();

    const uint4* hp4 = (const uint4*)hsh;
    const float* AgB = Ag + (int64_t)b * TT * GATES + tid;
    const uint4* wlB = wlds + tid;
    const bool mfma_first = (w < 4);   // SIMD pairs (w, w+4): invert phases

    #pragma unroll 1
    for (int st = 0; st < TT; st++) {
        // stream batch1 (row 8j+6): issued now, consumed in S1
        uint4 sb0 = WsF[24 * 512];
        uint4 sb1 = WsF[25 * 512];
        uint4 sb2 = WsF[26 * 512];
        uint4 sb3 = WsF[27 * 512];
        // this step's Ag rows: in flight until the tail (~whole step of cover)
        float ag0 = 0.f, ag1 = 0.f, ag2 = 0.f, ag3 = 0.f;
        if (tid < HT) {
            const float* An = AgB + (int64_t)st * GATES;
            ag0 = An[0];
            ag1 = An[HT];
            ag2 = An[2 * HT];
            ag3 = An[3 * HT];
        }

        float a0 = 0.f, a1 = 0.f, a2 = 0.f, a3 = 0.f;
        float a4 = 0.f, a5 = 0.f, a6 = 0.f, a7 = 0.f;
        uint4 hF0, hF1, hF2, hF3;

        auto phaseM = [&]() {
            f16x8 bf0 = *(const f16x8*)((const char*)hsh + 0   + 16 * quad);
            f16x8 bf1 = *(const f16x8*)((const char*)hsh + 64  + 16 * quad);
            f16x8 bf2 = *(const f16x8*)((const char*)hsh + 128 + 16 * quad);
            f16x8 bf3 = *(const f16x8*)((const char*)hsh + 192 + 16 * quad);
            #pragma unroll
            for (int pr = 0; pr < 4; pr++) {
                f32x4 am0 = {}, am1 = {};
                am0 = __builtin_amdgcn_mfma_f32_16x16x32_f16(wm[pr*8+0], bf0, am0, 0,0,0);
                am0 = __builtin_amdgcn_mfma_f32_16x16x32_f16(wm[pr*8+1], bf1, am0, 0,0,0);
                am0 = __builtin_amdgcn_mfma_f32_16x16x32_f16(wm[pr*8+2], bf2, am0, 0,0,0);
                am0 = __builtin_amdgcn_mfma_f32_16x16x32_f16(wm[pr*8+3], bf3, am0, 0,0,0);
                am1 = __builtin_amdgcn_mfma_f32_16x16x32_f16(wm[pr*8+4], bf0, am1, 0,0,0);
                am1 = __builtin_amdgcn_mfma_f32_16x16x32_f16(wm[pr*8+5], bf1, am1, 0,0,0);
                am1 = __builtin_amdgcn_mfma_f32_16x16x32_f16(wm[pr*8+6], bf2, am1, 0,0,0);
                am1 = __builtin_amdgcn_mfma_f32_16x16x32_f16(wm[pr*8+7], bf3, am1, 0,0,0);
                if ((lane & 15) == 0) {
                    *(f32x4*)&gshM[128 * w + 32 * pr + 4 * quad]      = am0;
                    *(f32x4*)&gshM[128 * w + 32 * pr + 16 + 4 * quad] = am1;
                }
            }
        };
        auto phaseF = [&]() {
            hF0 = hp4[16 + 4 * e + 0];
            hF1 = hp4[16 + 4 * e + 1];
            hF2 = hp4[16 + 4 * e + 2];
            hF3 = hp4[16 + 4 * e + 3];
            a0 = dot8(a0, wa[0],  hF0); a0 = dot8(a0, wa[1],  hF1);
            a0 = dot8(a0, wa[2],  hF2); a0 = dot8(a0, wa[3],  hF3);
            a1 = dot8(a1, wa[4],  hF0); a1 = dot8(a1, wa[5],  hF1);
            a1 = dot8(a1, wa[6],  hF2); a1 = dot8(a1, wa[7],  hF3);
            a2 = dot8(a2, wa[8],  hF0); a2 = dot8(a2, wa[9],  hF1);
            a2 = dot8(a2, wa[10], hF2); a2 = dot8(a2, wa[11], hF3);
            a3 = dot8(a3, wlB[0 * 512],  hF0); a3 = dot8(a3, wlB[1 * 512],  hF1);
            a3 = dot8(a3, wlB[2 * 512],  hF2); a3 = dot8(a3, wlB[3 * 512],  hF3);
            a4 = dot8(a4, wlB[4 * 512],  hF0); a4 = dot8(a4, wlB[5 * 512],  hF1);
            a4 = dot8(a4, wlB[6 * 512],  hF2); a4 = dot8(a4, wlB[7 * 512],  hF3);
            a5 = dot8(a5, wlB[8 * 512],  hF0); a5 = dot8(a5, wlB[9 * 512],  hF1);
            a5 = dot8(a5, wlB[10 * 512], hF2); a5 = dot8(a5, wlB[11 * 512], hF3);
        };
        auto phaseS1 = [&]() {      // row 8j+6; then issue batch2 (row 8j+7)
            a6 = dot8(a6, sb0, hF0); a6 = dot8(a6, sb1, hF1);
            a6 = dot8(a6, sb2, hF2); a6 = dot8(a6, sb3, hF3);
            sb0 = WsF[28 * 512]; sb1 = WsF[29 * 512];
            sb2 = WsF[30 * 512]; sb3 = WsF[31 * 512];
        };
        auto phaseS2 = [&]() {      // row 8j+7 (hF reloaded: cut liveness)
            uint4 g0 = hp4[16 + 4 * e + 0];
            uint4 g1 = hp4[16 + 4 * e + 1];
            uint4 g2 = hp4[16 + 4 * e + 2];
            uint4 g3 = hp4[16 + 4 * e + 3];
            a7 = dot8(a7, sb0, g0); a7 = dot8(a7, sb1, g1);
            a7 = dot8(a7, sb2, g2); a7 = dot8(a7, sb3, g3);
        };

        if (mfma_first) { phaseM(); phaseF(); phaseS1(); phaseS2(); }
        else            { phaseF(); phaseS1(); phaseM(); phaseS2(); }

        {
            int j = tid & 127;
            f32x4 vlo = {a0, a1, a2, a3};
            f32x4 vhi = {a4, a5, a6, a7};
            *(f32x4*)&gshF[e * GATES + 8 * j]     = vlo;
            *(f32x4*)&gshF[e * GATES + 8 * j + 4] = vhi;
        }
        WG_BARRIER();

        if (tid < HT) {
            float gi = gshM[tid] + gshF[tid] + gshF[GATES + tid]
                     + gshF[2 * GATES + tid] + gshF[3 * GATES + tid] + ag0;
            int r1 = HT + tid;
            float gf = gshM[r1] + gshF[r1] + gshF[GATES + r1]
                     + gshF[2 * GATES + r1] + gshF[3 * GATES + r1] + ag1;
            int r2 = 2 * HT + tid;
            float gg = gshM[r2] + gshF[r2] + gshF[GATES + r2]
                     + gshF[2 * GATES + r2] + gshF[3 * GATES + r2] + ag2;
            int r3 = 3 * HT + tid;
            float go = gshM[r3] + gshF[r3] + gshF[GATES + r3]
                     + gshF[2 * GATES + r3] + gshF[3 * GATES + r3] + ag3;
            c = fast_sig(gf) * c + fast_sig(gi) * fast_tanh(gg);
            float h = fast_sig(go) * fast_tanh(c);
            X[((int64_t)b * TT + st) * ldx + tid] = h;
            hsh[tid] = (half_t)h;
        }
        WG_BARRIER();
    }
}

// ---------------------------------------------------------------------------
__global__ __launch_bounds__(256) void softmax512_kernel(float* __restrict__ S)
{
    int row = blockIdx.x * 4 + (threadIdx.x >> 6);
    int lane = threadIdx.x & 63;
    float* p = S + (int64_t)row * 512 + lane * 8;
    float4 v0 = *(float4*)p;
    float4 v1 = *(float4*)(p + 4);
    float m = fmaxf(fmaxf(fmaxf(v0.x, v0.y), fmaxf(v0.z, v0.w)),
                    fmaxf(fmaxf(v1.x, v1.y), fmaxf(v1.z, v1.w)));
    #pragma unroll
    for (int off = 32; off; off >>= 1) m = fmaxf(m, __shfl_xor(m, off));
    v0.x = __expf(v0.x - m); v0.y = __expf(v0.y - m);
    v0.z = __expf(v0.z - m); v0.w = __expf(v0.w - m);
    v1.x = __expf(v1.x - m); v1.y = __expf(v1.y - m);
    v1.z = __expf(v1.z - m); v1.w = __expf(v1.w - m);
    float s = v0.x + v0.y + v0.z + v0.w + v1.x + v1.y + v1.z + v1.w;
    #pragma unroll
    for (int off = 32; off; off >>= 1) s += __shfl_xor(s, off);
    float inv = 1.0f / s;
    v0.x *= inv; v0.y *= inv; v0.z *= inv; v0.w *= inv;
    v1.x *= inv; v1.y *= inv; v1.z *= inv; v1.w *= inv;
    *(float4*)p = v0;
    *(float4*)(p + 4) = v1;
}

__global__ __launch_bounds__(256) void values_kernel(
    const float* __restrict__ Q, const float* __restrict__ L, float* __restrict__ V)
{
    int row = blockIdx.x * 4 + (threadIdx.x >> 6);
    int lane = threadIdx.x & 63;
    float2 q = *(const float2*)(Q + (int64_t)row * OO + lane * 2);
    float2 l = *(const float2*)(L + (int64_t)row * OO + lane * 2);
    float s = q.x * l.x + q.y * l.y;
    #pragma unroll
    for (int off = 32; off; off >>= 1) s += __shfl_xor(s, off);
    if (lane == 0) V[row] = s;
}

// ---------------------------------------------------------------------------
extern "C" void kernel_launch(void* const* d_in, const int* in_sizes, int n_in,
                              void* d_out, int out_size, void* d_ws, size_t ws_size,
                              hipStream_t stream)
{
    const float* enc      = (const float*)d_in[0];
    const float* h0       = (const float*)d_in[1];
    const float* c0       = (const float*)d_in[2];
    const int*   actions  = (const int*)  d_in[3];
    const float* emb_t    = (const float*)d_in[4];
    const float* Wih      = (const float*)d_in[5];
    const float* Whh      = (const float*)d_in[6];
    const float* bih      = (const float*)d_in[7];
    const float* bhh      = (const float*)d_in[8];
    const float* W_attn   = (const float*)d_in[9];
    const float* b_attn   = (const float*)d_in[10];
    const float* W_concat = (const float*)d_in[11];
    const float* b_concat = (const float*)d_in[12];
    const float* W_out    = (const float*)d_in[13];
    const float* W_critic = (const float*)d_in[14];
    const float* b_critic = (const float*)d_in[15];
    (void)in_sizes; (void)n_in; (void)out_size; (void)ws_size;

    const int M = BB * TT;                 // 32768

    float* out    = (float*)d_out;
    float* dact   = out;
    float* logits = out + M;
    float* values = out + M + (int64_t)M * OO;

    float* ws    = (float*)d_ws;
    float* gates = ws;
    float* xbuf  = ws + 33554432;
    float* cat   = ws + 41943040;
    float* keysR = ws + 58720256;
    float* keys  = keysR;
    uint4* Wpkh  = (uint4*)keysR;          // 1 MB; dead before keys
    float* scores = gates;
    float* qv     = gates;
    float* dec    = xbuf;

    const int64_t LWP = 32768;             // uint4s per layer in Wpkh
    const int64_t LW  = (int64_t)GATES * HT;

    // 1) embedding + decoder_action
    hipLaunchKernelGGL(embed_kernel, dim3(M), dim3(256), 0, stream,
                       actions, emb_t, xbuf, dact);
    // 2) repack Whh to fp16 hybrid layout
    hipLaunchKernelGGL(repack_whh_mfma_kernel, dim3(256), dim3(256), 0, stream,
                       Whh, Wpkh);
    // 3) layer-0 input GEMM (MFMA fp16): gates = emb @ Wih0^T + bih0 + bhh0
    hipLaunchKernelGGL((mfma_gemm_kernel<true, 0>), dim3(8, 256, 1), dim3(256), 0, stream,
                       xbuf, Wih, gates, HT, HT, HT, GATES,
                       (int64_t)0, (int64_t)0, (int64_t)0, bih, bhh);
    // 4) layer-0 recurrence -> X1 (xbuf, ldx=256)
    hipLaunchKernelGGL(lstm_rec_kernel, dim3(BB), dim3(512), 0, stream,
                       gates, Wpkh, h0, c0, xbuf, HT);
    // 5) layer-1 input GEMM (MFMA fp16)
    hipLaunchKernelGGL((mfma_gemm_kernel<true, 0>), dim3(8, 256, 1), dim3(256), 0, stream,
                       xbuf, Wih + LW, gates, HT, HT, HT, GATES,
                       (int64_t)0, (int64_t)0, (int64_t)0, bih + GATES, bhh + GATES);
    // 6) layer-1 recurrence -> cat[:, 0:256] (ldx=512)
    hipLaunchKernelGGL(lstm_rec_kernel, dim3(BB), dim3(512), 0, stream,
                       gates, Wpkh + LWP, h0 + BB * HT, c0 + BB * HT, cat, 2 * HT);
    // 7) keys = enc @ W_attn^T + b_attn (MFMA fp16; overwrites Wpkh region)
    hipLaunchKernelGGL((mfma_gemm_kernel<true, 0>), dim3(2, 256, 1), dim3(256), 0, stream,
                       enc, W_attn, keys, HT, HT, HT, HT,
                       (int64_t)0, (int64_t)0, (int64_t)0, b_attn, (const float*)nullptr);
    // 8) scores[b] = out[b] @ keys[b]^T  (fp32, precision-sensitive softmax input)
    hipLaunchKernelGGL((gemm128_kernel<true, 0>), dim3(4, 4, BB), dim3(256), 0, stream,
                       cat, keys, scores, HT, 2 * HT, HT, TT,
                       (int64_t)TT * 2 * HT, (int64_t)TT * HT, (int64_t)TT * TT,
                       (const float*)nullptr, (const float*)nullptr);
    // 9) softmax
    hipLaunchKernelGGL(softmax512_kernel, dim3(M / 4), dim3(256), 0, stream, scores);
    // 10) ctx[b] = P[b] @ enc[b] -> cat[:,256:]  (fp32)
    hipLaunchKernelGGL((gemm128_kernel<false, 0>), dim3(2, 4, BB), dim3(256), 0, stream,
                       scores, enc, cat + HT, TT, TT, HT, 2 * HT,
                       (int64_t)TT * TT, (int64_t)TT * HT, (int64_t)TT * 2 * HT,
                       (const float*)nullptr, (const float*)nullptr);
    // 11) dec = tanh(cat @ W_concat^T + b_concat) (MFMA fp16)
    hipLaunchKernelGGL((mfma_gemm_kernel<true, 1>), dim3(2, 256, 1), dim3(256), 0, stream,
                       cat, W_concat, dec, 2 * HT, 2 * HT, 2 * HT, HT,
                       (int64_t)0, (int64_t)0, (int64_t)0, b_concat, (const float*)nullptr);
    // 12) logits = dec @ W_out^T  (fp32 — output path)
    hipLaunchKernelGGL((gemm128_kernel<true, 0>), dim3(1, 256, 1), dim3(256), 0, stream,
                       dec, W_out, logits, HT, HT, HT, OO,
                       (int64_t)0, (int64_t)0, (int64_t)0,
                       (const float*)nullptr, (const float*)nullptr);
    // 13) qv = logits @ W_critic^T + b_critic  (fp32 — output path)
    hipLaunchKernelGGL((gemm128_kernel<true, 0>), dim3(1, 256, 1), dim3(256), 0, stream,
                       logits, W_critic, qv, OO, OO, OO, OO,
                       (int64_t)0, (int64_t)0, (int64_t)0, b_critic, (const float*)nullptr);
    // 14) values
    hipLaunchKernelGGL(values_kernel, dim3(M / 4), dim3(256), 0, stream,
                       qv, logits, values);
}

// Round 8
// 2058.072 us; speedup vs baseline: 3.0604x; 3.0604x over previous
//
#include <hip/hip_runtime.h>
#include <stdint.h>

// Problem constants
#define BB   64
#define TT   512
#define HT   256
#define OO   128
#define GATES 1024   // 4*H

// ---------------------------------------------------------------------------
// R17 recurrence: R15 4-CU row-split with the sync path overhauled.
// R15 measured: step 3470cy = ~600 compute + ~2900 sync.  Diagnosed sync
// flaws: (1) reader spin used atomicOr (RMW takes line EXCLUSIVE -> 3 reader
// waves + writer ping-pong ownership ~700cy/hand-off), (2) h published LAST
// in the tail (after X store), (3) extra combine barrier.
// R17: readers poll with plain sc0/sc1 system-coherent loads (no ownership
// transfer; still read the coherence point where atomicExch deposited the
// stamped word; stamp-validation preserves correctness; atomicOr fallback
// after 512 polls = hang insurance), publish h FIRST in the tail, combine
// folded into tail via agsh[] (2 barriers/step).
// Layout per layer (32768 uint4): idx = (q*16+u)*512 + t;
//   t: s=t>>8 (k-half), G=(t>>6)&3 (gate), rr=t&63;
//   row = 256*G + 64*q + rr;  k = 128*s + 8*u   (u=0..15)

typedef _Float16 half_t;
typedef _Float16 half2_t __attribute__((ext_vector_type(2)));
typedef _Float16 f16x8  __attribute__((ext_vector_type(8)));
typedef float    f32x4  __attribute__((ext_vector_type(4)));

__device__ __forceinline__ half2_t h2_(unsigned int x) {
    return __builtin_bit_cast(half2_t, x);
}
// lgkm-only workgroup barrier: no vmcnt drain per step.
#define WG_BARRIER() do { __builtin_amdgcn_s_waitcnt(0xC07F); \
                          __builtin_amdgcn_s_barrier(); } while (0)

__device__ __forceinline__ float fast_sig(float x) {
    return __builtin_amdgcn_rcpf(1.0f + __expf(-x));
}
__device__ __forceinline__ float fast_tanh(float x) {
    float t = __expf(2.0f * x);
    return 1.0f - 2.0f * __builtin_amdgcn_rcpf(t + 1.0f);
}

// 8-element fp16 dot: acc += w . h  (w, h as uint4 of packed half2)
__device__ __forceinline__ float dot8(float acc, uint4 wv, uint4 h4) {
    acc = __builtin_amdgcn_fdot2(h2_(wv.x), h2_(h4.x), acc, false);
    acc = __builtin_amdgcn_fdot2(h2_(wv.y), h2_(h4.y), acc, false);
    acc = __builtin_amdgcn_fdot2(h2_(wv.z), h2_(h4.z), acc, false);
    acc = __builtin_amdgcn_fdot2(h2_(wv.w), h2_(h4.w), acc, false);
    return acc;
}

// system-coherent load (bypasses L1/L2 -> reads the coherence point)
__device__ __forceinline__ unsigned int scload(const unsigned int* p) {
    unsigned long long a = (unsigned long long)p;
    unsigned int w;
    asm volatile("global_load_dword %0, %1, off sc0 sc1\n\ts_waitcnt vmcnt(0)"
                 : "=v"(w) : "v"(a) : "memory");
    return w;
}

// ---------------------------------------------------------------------------
// Embedding gather + decoder_action output
__global__ __launch_bounds__(256) void embed_kernel(
    const int* __restrict__ actions, const float* __restrict__ emb_table,
    float* __restrict__ X, float* __restrict__ dact)
{
    int row = blockIdx.x;
    int t = row & (TT - 1);
    int id = (t == 0) ? 0 : actions[row - 1];
    X[(int64_t)row * HT + threadIdx.x] = emb_table[(int64_t)id * HT + threadIdx.x];
    if (threadIdx.x == 0) dact[row] = (float)actions[row];
}

// ---------------------------------------------------------------------------
// Repack Whh to the R17 layout; zero the h-exchange buffers (HX) so stale
// stamps from a previous graph replay can never validate.
__global__ __launch_bounds__(256) void repack_whh_mfma_kernel(
    const float* __restrict__ Whh, uint4* __restrict__ Wpkh,
    unsigned int* __restrict__ HXall)
{
    int idx = blockIdx.x * 256 + threadIdx.x;   // 0..65535
    HXall[idx] = 0u;                             // 2 layers x 64b x 4q x 2par x 64

    int g = idx & 32767;
    int l = idx >> 15;
    int t = g & 511;
    int u = (g >> 9) & 15;
    int q = g >> 13;                             // 0..3
    int s = t >> 8, G = (t >> 6) & 3, rr = t & 63;
    int row = 256 * G + 64 * q + rr;
    int k   = 128 * s + 8 * u;

    const float* src = Whh + (int64_t)l * (GATES * HT) + (int64_t)row * HT + k;
    const float4 a = *(const float4*)(src);
    const float4 b = *(const float4*)(src + 4);
    half2_t p0 = {(half_t)a.x, (half_t)a.y};
    half2_t p1 = {(half_t)a.z, (half_t)a.w};
    half2_t p2 = {(half_t)b.x, (half_t)b.y};
    half2_t p3 = {(half_t)b.z, (half_t)b.w};
    uint4 o;
    o.x = __builtin_bit_cast(unsigned int, p0);
    o.y = __builtin_bit_cast(unsigned int, p1);
    o.z = __builtin_bit_cast(unsigned int, p2);
    o.w = __builtin_bit_cast(unsigned int, p3);
    Wpkh[idx] = o;
}

// ---------------------------------------------------------------------------
// MFMA fp16 GEMM: C = act( A @ op(B) + bias1 + bias2 ), fp32 in/out.
template<bool TRANS_B, int ACT>
__global__ __launch_bounds__(256) void mfma_gemm_kernel(
    const float* __restrict__ A, const float* __restrict__ Bm,
    float* __restrict__ C,
    int K, int lda, int ldb, int ldc,
    int64_t sA, int64_t sB, int64_t sC,
    const float* __restrict__ bias1, const float* __restrict__ bias2)
{
    constexpr int BM = 128, BN = 128, BK = 32;
    constexpr int LDT = BK + 8;                  // 40 halfs = 80 B row stride
    __shared__ __align__(16) half_t Asl[BM * LDT];   // 10 KB
    __shared__ __align__(16) half_t Bsl[BN * LDT];   // 10 KB

    const int tid  = threadIdx.x;
    const int wave = tid >> 6;
    const int lane = tid & 63;
    const int wm = (wave & 1) * 64;
    const int wn = (wave >> 1) * 64;
    const int m0 = blockIdx.y * BM;
    const int n0 = blockIdx.x * BN;
    A  += (int64_t)blockIdx.z * sA;
    Bm += (int64_t)blockIdx.z * sB;
    C  += (int64_t)blockIdx.z * sC;

    const int fm = lane & 15;
    const int qd = lane >> 4;

    f32x4 acc[4][4] = {};

    for (int k0 = 0; k0 < K; k0 += BK) {
        #pragma unroll
        for (int i = 0; i < 4; i++) {
            int idx = tid + i * 256;             // 0..1023
            int r  = idx >> 3;                   // 0..127
            int kq = idx & 7;                    // 0..7
            float4 v = *(const float4*)(A + (int64_t)(m0 + r) * lda + k0 + kq * 4);
            half_t* d = &Asl[r * LDT + kq * 4];
            d[0] = (half_t)v.x; d[1] = (half_t)v.y;
            d[2] = (half_t)v.z; d[3] = (half_t)v.w;
        }
        if (TRANS_B) {
            #pragma unroll
            for (int i = 0; i < 4; i++) {
                int idx = tid + i * 256;
                int r  = idx >> 3;
                int kq = idx & 7;
                float4 v = *(const float4*)(Bm + (int64_t)(n0 + r) * ldb + k0 + kq * 4);
                half_t* d = &Bsl[r * LDT + kq * 4];
                d[0] = (half_t)v.x; d[1] = (half_t)v.y;
                d[2] = (half_t)v.z; d[3] = (half_t)v.w;
            }
        } else {
            #pragma unroll
            for (int i = 0; i < 4; i++) {
                int idx = tid + i * 256;
                int kk = idx >> 5;               // 0..31
                int nq = idx & 31;               // 0..31 (x4 n)
                float4 v = *(const float4*)(Bm + (int64_t)(k0 + kk) * ldb + n0 + nq * 4);
                Bsl[(nq * 4 + 0) * LDT + kk] = (half_t)v.x;
                Bsl[(nq * 4 + 1) * LDT + kk] = (half_t)v.y;
                Bsl[(nq * 4 + 2) * LDT + kk] = (half_t)v.z;
                Bsl[(nq * 4 + 3) * LDT + kk] = (half_t)v.w;
            }
        }
        __syncthreads();

        f16x8 af[4], bf[4];
        #pragma unroll
        for (int t = 0; t < 4; t++)
            af[t] = *(const f16x8*)&Asl[(wm + t * 16 + fm) * LDT + qd * 8];
        #pragma unroll
        for (int t = 0; t < 4; t++)
            bf[t] = *(const f16x8*)&Bsl[(wn + t * 16 + fm) * LDT + qd * 8];
        #pragma unroll
        for (int mt = 0; mt < 4; mt++)
            #pragma unroll
            for (int nt = 0; nt < 4; nt++)
                acc[mt][nt] = __builtin_amdgcn_mfma_f32_16x16x32_f16(
                                  af[mt], bf[nt], acc[mt][nt], 0, 0, 0);
        __syncthreads();
    }

    #pragma unroll
    for (int nt = 0; nt < 4; nt++) {
        int n = n0 + wn + nt * 16 + fm;
        float bv = 0.0f;
        if (bias1) bv += bias1[n];
        if (bias2) bv += bias2[n];
        #pragma unroll
        for (int mt = 0; mt < 4; mt++) {
            #pragma unroll
            for (int r = 0; r < 4; r++) {
                int m = m0 + wm + mt * 16 + qd * 4 + r;
                float v = acc[mt][nt][r] + bv;
                if (ACT == 1) v = tanhf(v);
                C[(int64_t)m * ldc + n] = v;
            }
        }
    }
}

// ---------------------------------------------------------------------------
// Generic fp32 tiled GEMM (kept for attention + output chain precision).
template<bool TRANS_B, int ACT>
__global__ __launch_bounds__(256) void gemm128_kernel(
    const float* __restrict__ A, const float* __restrict__ Bm,
    float* __restrict__ C,
    int K, int lda, int ldb, int ldc,
    int64_t sA, int64_t sB, int64_t sC,
    const float* __restrict__ bias1, const float* __restrict__ bias2)
{
    constexpr int BM = 128, BN = 128, BK = 16;
    __shared__ __align__(16) float As[BK][BM + 4];
    __shared__ __align__(16) float Bs[BK][BN + 4];

    const int tid = threadIdx.x;
    const int m0 = blockIdx.y * BM;
    const int n0 = blockIdx.x * BN;
    A  += (int64_t)blockIdx.z * sA;
    Bm += (int64_t)blockIdx.z * sB;
    C  += (int64_t)blockIdx.z * sC;

    const int tm = tid & 15;
    const int tn = tid >> 4;

    float acc[8][8] = {};

    for (int k0 = 0; k0 < K; k0 += BK) {
        #pragma unroll
        for (int i = 0; i < 2; i++) {
            int idx = tid + i * 256;
            int ar = idx >> 2;
            int ak = (idx & 3) * 4;
            const float4 v = *(const float4*)(A + (int64_t)(m0 + ar) * lda + k0 + ak);
            As[ak + 0][ar] = v.x; As[ak + 1][ar] = v.y;
            As[ak + 2][ar] = v.z; As[ak + 3][ar] = v.w;
        }
        if (TRANS_B) {
            #pragma unroll
            for (int i = 0; i < 2; i++) {
                int idx = tid + i * 256;
                int br = idx >> 2;
                int bk = (idx & 3) * 4;
                const float4 v = *(const float4*)(Bm + (int64_t)(n0 + br) * ldb + k0 + bk);
                Bs[bk + 0][br] = v.x; Bs[bk + 1][br] = v.y;
                Bs[bk + 2][br] = v.z; Bs[bk + 3][br] = v.w;
            }
        } else {
            #pragma unroll
            for (int i = 0; i < 2; i++) {
                int idx = tid + i * 256;
                int bk = idx >> 5;
                int bn = (idx & 31) * 4;
                const float4 v = *(const float4*)(Bm + (int64_t)(k0 + bk) * ldb + n0 + bn);
                *(float4*)&Bs[bk][bn] = v;
            }
        }
        __syncthreads();

        #pragma unroll
        for (int k = 0; k < BK; k++) {
            float a[8], b[8];
            *(float4*)&a[0] = *(const float4*)&As[k][tm * 8];
            *(float4*)&a[4] = *(const float4*)&As[k][tm * 8 + 4];
            *(float4*)&b[0] = *(const float4*)&Bs[k][tn * 8];
            *(float4*)&b[4] = *(const float4*)&Bs[k][tn * 8 + 4];
            #pragma unroll
            for (int i = 0; i < 8; i++)
                #pragma unroll
                for (int j = 0; j < 8; j++)
                    acc[i][j] += a[i] * b[j];
        }
        __syncthreads();
    }

    float bv[8];
    #pragma unroll
    for (int j = 0; j < 8; j++) {
        int n = n0 + tn * 8 + j;
        float b = 0.0f;
        if (bias1) b += bias1[n];
        if (bias2) b += bias2[n];
        bv[j] = b;
    }
    #pragma unroll
    for (int i = 0; i < 8; i++) {
        int64_t m = m0 + tm * 8 + i;
        float o[8];
        #pragma unroll
        for (int j = 0; j < 8; j++) {
            float v = acc[i][j] + bv[j];
            if (ACT == 1) v = tanhf(v);
            o[j] = v;
        }
        *(float4*)(C + m * ldc + n0 + tn * 8)     = make_float4(o[0], o[1], o[2], o[3]);
        *(float4*)(C + m * ldc + n0 + tn * 8 + 4) = make_float4(o[4], o[5], o[6], o[7]);
    }
}

// ---------------------------------------------------------------------------
// LSTM recurrence (R17: 4-CU split, sc-load sync). grid = 256 blocks
// (b = blk>>2, q = blk&3), 512 threads; grid <= CU count -> all co-resident.
__global__ __launch_bounds__(512)
__attribute__((amdgpu_waves_per_eu(2, 2)))
void lstm_rec_kernel(
    const float* __restrict__ Ag,
    const uint4* __restrict__ Wpk,
    const float* __restrict__ h0l,
    const float* __restrict__ c0l,
    float* __restrict__ X, int ldx,
    unsigned int* __restrict__ HX)
{
    const int bq  = blockIdx.x;
    const int b   = bq >> 2;
    const int q   = bq & 3;
    const int tid = threadIdx.x;
    const int s   = tid >> 8;        // k-half

    __shared__ __align__(16) float          part[512];   // 2 KB
    __shared__ __align__(16) float          agsh[256];   // 1 KB (input-gate bias)
    __shared__ __align__(16) unsigned short hsh[HT];     // 512 B

    // weights: 16 uint4 = 64 arch VGPRs, fully resident
    uint4 wv[16];
    {
        const uint4* Wq = Wpk + (q * 16) * 512 + tid;
        #pragma unroll
        for (int u = 0; u < 16; u++) wv[u] = Wq[u * 512];
    }

    // init full h in LDS; own-quarter c in regs (threads 0..63)
    if (tid < HT) {
        half_t hv = (half_t)h0l[b * HT + tid];
        hsh[tid] = __builtin_bit_cast(unsigned short, hv);
    }
    float c = 0.0f;
    if (tid < 64) c = c0l[b * HT + 64 * q + tid];

    // Ag base for this thread's gate row (threads 0..255 use it)
    const float* AgB = Ag + (int64_t)b * TT * GATES
                     + (256 * ((tid >> 6) & 3) + 64 * q + (tid & 63));
    unsigned int* HXb = HX + b * 512;   // 4q x 2par x 64 words

    // partner-fetch assignment: waves 1..3, one wave per partner quarter
    int wq = 0, wi = 0;
    if (tid >= 64 && tid < 256) {
        int i = tid - 64;
        int p = i >> 6;
        wq = p + (p >= q ? 1 : 0);
        wi = i & 63;
    }

    const uint4* hp4 = (const uint4*)hsh;
    float agc = 0.0f;
    if (tid < 256) agc = AgB[0];
    __syncthreads();

    #pragma unroll 1
    for (int st = 0; st < TT; st++) {
        // prefetch next step's Ag (consumed via agsh one step later)
        float agn = 0.0f;
        {
            int stn = (st + 1 < TT) ? st + 1 : st;
            if (tid < 256) agn = AgB[(int64_t)stn * GATES];
        }
        // fetch partner h-quarters (version st): stamp-validated words,
        // plain sc0/sc1 loads (no RMW ownership ping-pong); atomicOr fallback.
        if (st > 0 && tid >= 64 && tid < 256) {
            unsigned int* src = HXb + wq * 128 + (st & 1) * 64 + wi;
            unsigned int w = scload(src);
            int tries = 0;
            while ((w >> 16) != (unsigned)st) {
                if (++tries > 512) {
                    w = atomicOr(src, 0u);
                    tries = 0;
                } else {
                    w = scload(src);
                }
            }
            hsh[64 * wq + wi] = (unsigned short)(w & 0xffffu);
        }
        WG_BARRIER();                            // hsh complete

        // dot: own row, own k-half (h chunks are wave-uniform LDS broadcasts)
        float a = 0.0f;
        #pragma unroll
        for (int u = 0; u < 16; u++)
            a = dot8(a, wv[u], hp4[16 * s + u]);
        part[tid] = a;
        if (tid < 256) agsh[tid] = agc;
        WG_BARRIER();

        // tail: combine + gates + publish FIRST, then X store + hsh
        if (tid < 64) {
            float gi = part[tid]       + part[256 + tid]       + agsh[tid];
            float gf = part[64 + tid]  + part[320 + tid]       + agsh[64 + tid];
            float gg = part[128 + tid] + part[384 + tid]       + agsh[128 + tid];
            float go = part[192 + tid] + part[448 + tid]       + agsh[192 + tid];
            c = fast_sig(gf) * c + fast_sig(gi) * fast_tanh(gg);
            float h = fast_sig(go) * fast_tanh(c);
            half_t hh = (half_t)h;
            unsigned short hb = __builtin_bit_cast(unsigned short, hh);
            if (st + 1 < TT) {
                unsigned int word = ((unsigned)(st + 1) << 16) | (unsigned)hb;
                atomicExch(HXb + q * 128 + ((st + 1) & 1) * 64 + tid, word);
            }
            X[((int64_t)b * TT + st) * ldx + 64 * q + tid] = h;
            hsh[64 * q + tid] = hb;
        }
        agc = agn;
        // no trailing barrier: next iteration's WG_BARRIER (post-fetch) orders
        // the tail's hsh/part accesses against the next dot phase.
    }
}

// ---------------------------------------------------------------------------
__global__ __launch_bounds__(256) void softmax512_kernel(float* __restrict__ S)
{
    int row = blockIdx.x * 4 + (threadIdx.x >> 6);
    int lane = threadIdx.x & 63;
    float* p = S + (int64_t)row * 512 + lane * 8;
    float4 v0 = *(float4*)p;
    float4 v1 = *(float4*)(p + 4);
    float m = fmaxf(fmaxf(fmaxf(v0.x, v0.y), fmaxf(v0.z, v0.w)),
                    fmaxf(fmaxf(v1.x, v1.y), fmaxf(v1.z, v1.w)));
    #pragma unroll
    for (int off = 32; off; off >>= 1) m = fmaxf(m, __shfl_xor(m, off));
    v0.x = __expf(v0.x - m); v0.y = __expf(v0.y - m);
    v0.z = __expf(v0.z - m); v0.w = __expf(v0.w - m);
    v1.x = __expf(v1.x - m); v1.y = __expf(v1.y - m);
    v1.z = __expf(v1.z - m); v1.w = __expf(v1.w - m);
    float s = v0.x + v0.y + v0.z + v0.w + v1.x + v1.y + v1.z + v1.w;
    #pragma unroll
    for (int off = 32; off; off >>= 1) s += __shfl_xor(s, off);
    float inv = 1.0f / s;
    v0.x *= inv; v0.y *= inv; v0.z *= inv; v0.w *= inv;
    v1.x *= inv; v1.y *= inv; v1.z *= inv; v1.w *= inv;
    *(float4*)p = v0;
    *(float4*)(p + 4) = v1;
}

__global__ __launch_bounds__(256) void values_kernel(
    const float* __restrict__ Q, const float* __restrict__ L, float* __restrict__ V)
{
    int row = blockIdx.x * 4 + (threadIdx.x >> 6);
    int lane = threadIdx.x & 63;
    float2 q = *(const float2*)(Q + (int64_t)row * OO + lane * 2);
    float2 l = *(const float2*)(L + (int64_t)row * OO + lane * 2);
    float s = q.x * l.x + q.y * l.y;
    #pragma unroll
    for (int off = 32; off; off >>= 1) s += __shfl_xor(s, off);
    if (lane == 0) V[row] = s;
}

// ---------------------------------------------------------------------------
extern "C" void kernel_launch(void* const* d_in, const int* in_sizes, int n_in,
                              void* d_out, int out_size, void* d_ws, size_t ws_size,
                              hipStream_t stream)
{
    const float* enc      = (const float*)d_in[0];
    const float* h0       = (const float*)d_in[1];
    const float* c0       = (const float*)d_in[2];
    const int*   actions  = (const int*)  d_in[3];
    const float* emb_t    = (const float*)d_in[4];
    const float* Wih      = (const float*)d_in[5];
    const float* Whh      = (const float*)d_in[6];
    const float* bih      = (const float*)d_in[7];
    const float* bhh      = (const float*)d_in[8];
    const float* W_attn   = (const float*)d_in[9];
    const float* b_attn   = (const float*)d_in[10];
    const float* W_concat = (const float*)d_in[11];
    const float* b_concat = (const float*)d_in[12];
    const float* W_out    = (const float*)d_in[13];
    const float* W_critic = (const float*)d_in[14];
    const float* b_critic = (const float*)d_in[15];
    (void)in_sizes; (void)n_in; (void)out_size; (void)ws_size;

    const int M = BB * TT;                 // 32768

    float* out    = (float*)d_out;
    float* dact   = out;
    float* logits = out + M;
    float* values = out + M + (int64_t)M * OO;

    float* ws    = (float*)d_ws;
    float* gates = ws;
    float* xbuf  = ws + 33554432;
    float* cat   = ws + 41943040;
    float* keysR = ws + 58720256;
    float* keys  = keysR;
    uint4* Wpkh  = (uint4*)keysR;          // 1 MB; dead before keys written
    unsigned int* HX0 = (unsigned int*)(ws + 59000000);  // 128 KB, dead before keys
    unsigned int* HX1 = HX0 + 32768;
    float* scores = gates;
    float* qv     = gates;
    float* dec    = xbuf;

    const int64_t LWP = 32768;             // uint4s per layer in Wpkh
    const int64_t LW  = (int64_t)GATES * HT;

    // 1) embedding + decoder_action
    hipLaunchKernelGGL(embed_kernel, dim3(M), dim3(256), 0, stream,
                       actions, emb_t, xbuf, dact);
    // 2) repack Whh + zero h-exchange buffers
    hipLaunchKernelGGL(repack_whh_mfma_kernel, dim3(256), dim3(256), 0, stream,
                       Whh, Wpkh, HX0);
    // 3) layer-0 input GEMM (MFMA fp16): gates = emb @ Wih0^T + bih0 + bhh0
    hipLaunchKernelGGL((mfma_gemm_kernel<true, 0>), dim3(8, 256, 1), dim3(256), 0, stream,
                       xbuf, Wih, gates, HT, HT, HT, GATES,
                       (int64_t)0, (int64_t)0, (int64_t)0, bih, bhh);
    // 4) layer-0 recurrence -> X1 (xbuf, ldx=256)
    hipLaunchKernelGGL(lstm_rec_kernel, dim3(BB * 4), dim3(512), 0, stream,
                       gates, Wpkh, h0, c0, xbuf, HT, HX0);
    // 5) layer-1 input GEMM (MFMA fp16)
    hipLaunchKernelGGL((mfma_gemm_kernel<true, 0>), dim3(8, 256, 1), dim3(256), 0, stream,
                       xbuf, Wih + LW, gates, HT, HT, HT, GATES,
                       (int64_t)0, (int64_t)0, (int64_t)0, bih + GATES, bhh + GATES);
    // 6) layer-1 recurrence -> cat[:, 0:256] (ldx=512)
    hipLaunchKernelGGL(lstm_rec_kernel, dim3(BB * 4), dim3(512), 0, stream,
                       gates, Wpkh + LWP, h0 + BB * HT, c0 + BB * HT, cat, 2 * HT, HX1);
    // 7) keys = enc @ W_attn^T + b_attn (MFMA fp16; overwrites Wpkh/HX region)
    hipLaunchKernelGGL((mfma_gemm_kernel<true, 0>), dim3(2, 256, 1), dim3(256), 0, stream,
                       enc, W_attn, keys, HT, HT, HT, HT,
                       (int64_t)0, (int64_t)0, (int64_t)0, b_attn, (const float*)nullptr);
    // 8) scores[b] = out[b] @ keys[b]^T  (fp32, precision-sensitive softmax input)
    hipLaunchKernelGGL((gemm128_kernel<true, 0>), dim3(4, 4, BB), dim3(256), 0, stream,
                       cat, keys, scores, HT, 2 * HT, HT, TT,
                       (int64_t)TT * 2 * HT, (int64_t)TT * HT, (int64_t)TT * TT,
                       (const float*)nullptr, (const float*)nullptr);
    // 9) softmax
    hipLaunchKernelGGL(softmax512_kernel, dim3(M / 4), dim3(256), 0, stream, scores);
    // 10) ctx[b] = P[b] @ enc[b] -> cat[:,256:]  (fp32)
    hipLaunchKernelGGL((gemm128_kernel<false, 0>), dim3(2, 4, BB), dim3(256), 0, stream,
                       scores, enc, cat + HT, TT, TT, HT, 2 * HT,
                       (int64_t)TT * TT, (int64_t)TT * HT, (int64_t)TT * 2 * HT,
                       (const float*)nullptr, (const float*)nullptr);
    // 11) dec = tanh(cat @ W_concat^T + b_concat) (MFMA fp16)
    hipLaunchKernelGGL((mfma_gemm_kernel<true, 1>), dim3(2, 256, 1), dim3(256), 0, stream,
                       cat, W_concat, dec, 2 * HT, 2 * HT, 2 * HT, HT,
                       (int64_t)0, (int64_t)0, (int64_t)0, b_concat, (const float*)nullptr);
    // 12) logits = dec @ W_out^T  (fp32 — output path)
    hipLaunchKernelGGL((gemm128_kernel<true, 0>), dim3(1, 256, 1), dim3(256), 0, stream,
                       dec, W_out, logits, HT, HT, HT, OO,
                       (int64_t)0, (int64_t)0, (int64_t)0,
                       (const float*)nullptr, (const float*)nullptr);
    // 13) qv = logits @ W_critic^T + b_critic  (fp32 — output path)
    hipLaunchKernelGGL((gemm128_kernel<true, 0>), dim3(1, 256, 1), dim3(256), 0, stream,
                       logits, W_critic, qv, OO, OO, OO, OO,
                       (int64_t)0, (int64_t)0, (int64_t)0, b_critic, (const float*)nullptr);
    // 14) values
    hipLaunchKernelGGL(values_kernel, dim3(M / 4), dim3(256), 0, stream,
                       qv, logits, values);
}